// Round 5
// baseline (262.110 us; speedup 1.0000x reference)
//
#include <hip/hip_runtime.h>
#include <math.h>

#define IMG_W 512
#define IMG_H 512
#define NB 32
#define NC 3
#define PLANE (IMG_H * IMG_W)      // 262144 px per channel

#define TILE_W 32
#define TILE_H 32
#define TILES_X (IMG_W / TILE_W)   // 16
#define TILES_Y (IMG_H / TILE_H)   // 16
#define TILES_PER_B (TILES_X * TILES_Y)  // 256
#define NBLOCKS (NB * TILES_PER_B)       // 8192

typedef float vfloat4 __attribute__((ext_vector_type(4)));

// ws layout (canonical): ws[b*256+tile] = num, ws[NBLOCKS + b*256+tile] = den.

__global__ __launch_bounds__(256, 7) void recon_main(
    const float* __restrict__ theta,
    const float* __restrict__ img_R,
    const float* __restrict__ img_orig,
    float* __restrict__ ws)
{
    __shared__ float snum[4];
    __shared__ float sden[4];

    // --- load-balanced decode: each of the 8 dispatch streams (lin%8, ~XCD)
    // processes 1/8 of EVERY batch in 32-tile chunks (2 tile-rows), so heavy
    // batches (bbox cost ~ s^2) are spread evenly across streams AND across
    // blockIdx-space. Bijective: lin <-> (b, tile).
    const int lin  = blockIdx.x;       // 0..8191
    const int k    = lin & 7;          // stream id
    const int i    = lin >> 3;         // 0..1023
    const int step = i >> 5;           // 0..31
    const int t    = i & 31;           // 0..31 tile within chunk
    const int b    = (4 * k + step) & 31;
    const int chk  = ((b >> 2) - k) & 7;
    const int tile = chk * 32 + t;     // 0..255
    const int tx = (tile & (TILES_X - 1)) * TILE_W;
    const int ty = (tile >> 4) * TILE_H;
    const int gcan = b * TILES_PER_B + tile;   // canonical ws slot

    const int tid  = threadIdx.x;
    const int trow = tid >> 3;         // 0..31 (8 threads per tile row)
    const int tcol = (tid & 7) * 4;    // 0..28

    const int h  = ty + trow;
    const int w0 = tx + tcol;
    const int p0 = h * IMG_W + w0;

    const float* orig_b = img_orig + (size_t)b * NC * PLANE;
    const float* R_b    = img_R    + (size_t)b * NC * PLANE;

    // --- hoisted img_R loads: latency hides under weight/address math
    const vfloat4 rv0 = *(const vfloat4*)(R_b + 0 * PLANE + p0);
    const vfloat4 rv1 = *(const vfloat4*)(R_b + 1 * PLANE + p0);
    const vfloat4 rv2 = *(const vfloat4*)(R_b + 2 * PLANE + p0);

    // --- per-batch affine (uniform across block) ---
    const float ang   = theta[b * 3 + 0];
    const float s     = theta[b * 3 + 1];
    const float shift = 100.0f * theta[b * 3 + 2];
    float sn, cs;
    sincosf(ang, &sn, &cs);
    const float alpha = s * cs;
    const float beta  = s * sn;
    const float tx_a = (1.0f - alpha) * 256.0f - beta * 256.0f + shift;
    const float ty_a = beta * 256.0f + (1.0f - alpha) * 256.0f;
    const float Cc = alpha + beta + 2.0f * tx_a / 511.0f - 1.0f;
    const float Fc = -beta + alpha + 2.0f * ty_a / 511.0f - 1.0f;
    // source coords: x = X0 + alpha*w + beta*h ; y = Y0 - beta*w + alpha*h
    const float X0 = 255.5f * (Cc + 1.0f - alpha - beta);
    const float Y0 = 255.5f * (Fc + 1.0f + beta - alpha);

    const float xb = X0 + alpha * (float)w0 + beta * (float)h;
    const float yb = Y0 - beta * (float)w0 + alpha * (float)h;

    int   xi0a[4], xi1a[4], yi0a[4], yi1a[4];
    float w00[4], w10[4], w01[4], w11[4], mk[4];
    float den_acc = 0.0f;

#pragma unroll
    for (int j = 0; j < 4; ++j) {
        const float x = xb + alpha * (float)j;
        const float y = yb - beta  * (float)j;
        const float x0f = floorf(x), y0f = floorf(y);
        const float fx1 = x - x0f,  fy1 = y - y0f;
        const float fx0 = 1.0f - fx1, fy0 = 1.0f - fy1;
        const float vx0 = (x0f >=  0.0f && x0f <= 511.0f) ? 1.0f : 0.0f;
        const float vx1 = (x0f >= -1.0f && x0f <= 510.0f) ? 1.0f : 0.0f;
        const float vy0 = (y0f >=  0.0f && y0f <= 511.0f) ? 1.0f : 0.0f;
        const float vy1 = (y0f >= -1.0f && y0f <= 510.0f) ? 1.0f : 0.0f;
        xi0a[j] = (int)fminf(fmaxf(x0f,        0.0f), 511.0f);
        xi1a[j] = (int)fminf(fmaxf(x0f + 1.0f, 0.0f), 511.0f);
        yi0a[j] = (int)fminf(fmaxf(y0f,        0.0f), 511.0f);
        yi1a[j] = (int)fminf(fmaxf(y0f + 1.0f, 0.0f), 511.0f);
        w00[j] = fx0 * fy0 * vx0 * vy0;
        w10[j] = fx1 * fy0 * vx1 * vy0;
        w01[j] = fx0 * fy1 * vx0 * vy1;
        w11[j] = fx1 * fy1 * vx1 * vy1;
        mk[j]  = w00[j] + w10[j] + w01[j] + w11[j];
        den_acc += mk[j];
    }

    // --- direct bilinear gather for ALL blocks (no LDS staging, no stage
    // barrier): small bboxes hit L1, mid bboxes hit L2; 7 blocks/CU of TLP
    // hides the latency. Same expression tree / accumulation order as before.
    int a0i[4], a1i[4], sl0[4], sl1[4];
#pragma unroll
    for (int j = 0; j < 4; ++j) {
        const int xc = min(xi0a[j], 510);
        a0i[j] = yi0a[j] * IMG_W + xc;
        a1i[j] = yi1a[j] * IMG_W + xc;
        sl0[j] = xi0a[j] - xc;
        sl1[j] = xi1a[j] - xc;
    }

    float nrm[4] = {0.0f, 0.0f, 0.0f, 0.0f};
#pragma unroll
    for (int c = 0; c < NC; ++c) {
        const float* plane = orig_b + c * PLANE;
        const vfloat4 rv = (c == 0) ? rv0 : (c == 1) ? rv1 : rv2;
        const float rj[4] = {rv.x, rv.y, rv.z, rv.w};
#pragma unroll
        for (int j = 0; j < 4; ++j) {
            const float2 t0 = *(const float2*)(plane + a0i[j]);
            const float2 t1 = *(const float2*)(plane + a1i[j]);
            const float s00 = sl0[j] ? t0.y : t0.x;
            const float s10 = sl1[j] ? t0.y : t0.x;
            const float s01 = sl0[j] ? t1.y : t1.x;
            const float s11 = sl1[j] ? t1.y : t1.x;
            const float warped = s00 * w00[j] + s10 * w10[j]
                               + s01 * w01[j] + s11 * w11[j];
            nrm[j] += fabsf(rj[j] - warped);
        }
    }

    float num_acc = 0.0f;
#pragma unroll
    for (int j = 0; j < 4; ++j) num_acc += mk[j] * nrm[j];

    // --- wave (64) reduction ---
#pragma unroll
    for (int off = 32; off > 0; off >>= 1) {
        num_acc += __shfl_down(num_acc, off);
        den_acc += __shfl_down(den_acc, off);
    }

    const int wave = threadIdx.x >> 6;
    const int lane = threadIdx.x & 63;
    if (lane == 0) { snum[wave] = num_acc; sden[wave] = den_acc; }
    __syncthreads();
    if (threadIdx.x == 0) {
        ws[gcan]           = snum[0] + snum[1] + snum[2] + snum[3];
        ws[NBLOCKS + gcan] = sden[0] + sden[1] + sden[2] + sden[3];
    }
}

__global__ __launch_bounds__(256) void recon_final(
    const float* __restrict__ ws,
    float* __restrict__ out)
{
    __shared__ float sloss[NB];
    const int t = threadIdx.x;
    const int b = t >> 3;              // 0..31 (8 threads per batch)
    const int j = t & 7;               // 0..7

    // canonical ws layout; same per-lane tile order as before (j*32+k ascending)
    float n = 0.0f, d = 0.0f;
    for (int k = 0; k < 32; ++k) {
        const int tile = j * 32 + k;
        const int g    = b * TILES_PER_B + tile;
        n += ws[g];
        d += ws[NBLOCKS + g];
    }
#pragma unroll
    for (int off = 4; off > 0; off >>= 1) {
        n += __shfl_down(n, off);
        d += __shfl_down(d, off);
    }
    if (j == 0) sloss[b] = 10.0f * (n + 1e-16f) / (d + 1e-16f);
    __syncthreads();
    if (t == 0) {
        float L = 0.0f;
#pragma unroll
        for (int i = 0; i < NB; ++i) L += sloss[i];
        out[0] = L * (1.0f / (float)NB);
    }
}

extern "C" void kernel_launch(void* const* d_in, const int* in_sizes, int n_in,
                              void* d_out, int out_size, void* d_ws, size_t ws_size,
                              hipStream_t stream) {
    const float* theta    = (const float*)d_in[0];
    const float* img_R    = (const float*)d_in[1];
    const float* img_orig = (const float*)d_in[2];
    float* out = (float*)d_out;
    float* ws  = (float*)d_ws;

    recon_main<<<NBLOCKS, 256, 0, stream>>>(theta, img_R, img_orig, ws);
    recon_final<<<1, 256, 0, stream>>>(ws, out);
}

// Round 6
// 222.845 us; speedup vs baseline: 1.1762x; 1.1762x over previous
//
#include <hip/hip_runtime.h>
#include <math.h>

#define IMG_W 512
#define IMG_H 512
#define NB 32
#define NC 3
#define PLANE (IMG_H * IMG_W)      // 262144 px per channel

#define TILE_W 32
#define TILE_H 32
#define TILES_X (IMG_W / TILE_W)   // 16
#define TILES_Y (IMG_H / TILE_H)   // 16
#define TILES_PER_B (TILES_X * TILES_Y)  // 256
#define NBLOCKS (NB * TILES_PER_B)       // 8192

#define LDSC 4096                  // per-buffer staging floats (16 KB)
// two ping-pong buffers -> 32 KB -> 4 blocks/CU (was 48 KB / 3 blocks/CU)

typedef float vfloat4 __attribute__((ext_vector_type(4)));

// ws layout (canonical): ws[b*256+tile] = num, ws[NBLOCKS + b*256+tile] = den.

__global__ __launch_bounds__(256, 4) void recon_main(
    const float* __restrict__ theta,
    const float* __restrict__ img_R,
    const float* __restrict__ img_orig,
    float* __restrict__ ws)
{
    __shared__ __align__(16) float tileLds[2 * LDSC + 8];
    __shared__ float snum[4];
    __shared__ float sden[4];

    // --- load-balanced decode: each of the 8 dispatch streams (lin%8, ~XCD)
    // processes 1/8 of EVERY batch in 32-tile chunks. Bijective lin <-> (b,tile).
    const int lin  = blockIdx.x;       // 0..8191
    const int k    = lin & 7;          // stream id
    const int i    = lin >> 3;         // 0..1023
    const int step = i >> 5;           // 0..31
    const int t    = i & 31;           // 0..31 tile within chunk
    const int b    = (4 * k + step) & 31;
    const int chk  = ((b >> 2) - k) & 7;
    const int tile = chk * 32 + t;     // 0..255
    const int tx = (tile & (TILES_X - 1)) * TILE_W;
    const int ty = (tile >> 4) * TILE_H;
    const int gcan = b * TILES_PER_B + tile;   // canonical ws slot

    const int tid  = threadIdx.x;
    const int trow = tid >> 3;         // 0..31 (8 threads per tile row)
    const int tcol = (tid & 7) * 4;    // 0..28

    const int h  = ty + trow;
    const int w0 = tx + tcol;
    const int p0 = h * IMG_W + w0;

    const float* orig_b = img_orig + (size_t)b * NC * PLANE;
    const float* R_b    = img_R    + (size_t)b * NC * PLANE;

    // --- hoisted img_R loads: latency hides under weight math + staging
    const vfloat4 rv0 = *(const vfloat4*)(R_b + 0 * PLANE + p0);
    const vfloat4 rv1 = *(const vfloat4*)(R_b + 1 * PLANE + p0);
    const vfloat4 rv2 = *(const vfloat4*)(R_b + 2 * PLANE + p0);

    // --- per-batch affine (uniform across block) ---
    const float ang   = theta[b * 3 + 0];
    const float s     = theta[b * 3 + 1];
    const float shift = 100.0f * theta[b * 3 + 2];
    float sn, cs;
    sincosf(ang, &sn, &cs);
    const float alpha = s * cs;
    const float beta  = s * sn;
    const float tx_a = (1.0f - alpha) * 256.0f - beta * 256.0f + shift;
    const float ty_a = beta * 256.0f + (1.0f - alpha) * 256.0f;
    const float Cc = alpha + beta + 2.0f * tx_a / 511.0f - 1.0f;
    const float Fc = -beta + alpha + 2.0f * ty_a / 511.0f - 1.0f;
    // source coords: x = X0 + alpha*w + beta*h ; y = Y0 - beta*w + alpha*h
    const float X0 = 255.5f * (Cc + 1.0f - alpha - beta);
    const float Y0 = 255.5f * (Fc + 1.0f + beta - alpha);

    const float xb = X0 + alpha * (float)w0 + beta * (float)h;
    const float yb = Y0 - beta * (float)w0 + alpha * (float)h;

    int   xi0a[4], xi1a[4], yi0a[4], yi1a[4];
    float w00[4], w10[4], w01[4], w11[4], mk[4];
    float den_acc = 0.0f;

#pragma unroll
    for (int j = 0; j < 4; ++j) {
        const float x = xb + alpha * (float)j;
        const float y = yb - beta  * (float)j;
        const float x0f = floorf(x), y0f = floorf(y);
        const float fx1 = x - x0f,  fy1 = y - y0f;
        const float fx0 = 1.0f - fx1, fy0 = 1.0f - fy1;
        const float vx0 = (x0f >=  0.0f && x0f <= 511.0f) ? 1.0f : 0.0f;
        const float vx1 = (x0f >= -1.0f && x0f <= 510.0f) ? 1.0f : 0.0f;
        const float vy0 = (y0f >=  0.0f && y0f <= 511.0f) ? 1.0f : 0.0f;
        const float vy1 = (y0f >= -1.0f && y0f <= 510.0f) ? 1.0f : 0.0f;
        xi0a[j] = (int)fminf(fmaxf(x0f,        0.0f), 511.0f);
        xi1a[j] = (int)fminf(fmaxf(x0f + 1.0f, 0.0f), 511.0f);
        yi0a[j] = (int)fminf(fmaxf(y0f,        0.0f), 511.0f);
        yi1a[j] = (int)fminf(fmaxf(y0f + 1.0f, 0.0f), 511.0f);
        w00[j] = fx0 * fy0 * vx0 * vy0;
        w10[j] = fx1 * fy0 * vx1 * vy0;
        w01[j] = fx0 * fy1 * vx0 * vy1;
        w11[j] = fx1 * fy1 * vx1 * vy1;
        mk[j]  = w00[j] + w10[j] + w01[j] + w11[j];
        den_acc += mk[j];
    }

    // --- block-uniform source bbox (extrema of affine map are at tile corners) ---
    const float fx_lo = (float)tx, fx_hi = (float)(tx + TILE_W - 1);
    const float fy_lo = (float)ty, fy_hi = (float)(ty + TILE_H - 1);
    const float cxA = X0 + alpha * fx_lo + beta * fy_lo;
    const float cxB = X0 + alpha * fx_hi + beta * fy_lo;
    const float cxC = X0 + alpha * fx_lo + beta * fy_hi;
    const float cxD = X0 + alpha * fx_hi + beta * fy_hi;
    const float cyA = Y0 - beta * fx_lo + alpha * fy_lo;
    const float cyB = Y0 - beta * fx_hi + alpha * fy_lo;
    const float cyC = Y0 - beta * fx_lo + alpha * fy_hi;
    const float cyD = Y0 - beta * fx_hi + alpha * fy_hi;
    const float min_x = fminf(fminf(cxA, cxB), fminf(cxC, cxD));
    const float max_x = fmaxf(fmaxf(cxA, cxB), fmaxf(cxC, cxD));
    const float min_y = fminf(fminf(cyA, cyB), fminf(cyC, cyD));
    const float max_y = fmaxf(fmaxf(cyA, cyB), fmaxf(cyC, cyD));

    int xlo = (int)floorf(min_x);
    int xhi = (int)floorf(max_x) + 1;
    xlo = min(max(xlo, 0), 511);
    xhi = min(max(xhi, 0), 511);
    xlo &= ~3;                          // 16B-align staging rows
    int ylo = (int)floorf(min_y);
    int yhi = (int)floorf(max_y) + 1;
    ylo = min(max(ylo, 0), 511);
    yhi = min(max(yhi, 0), 511);

    const int bw = xhi - xlo + 1;
    const int bh = yhi - ylo + 1;
    int stride = (bw + 3) & ~3;
    if (((stride >> 2) & 1) == 0) stride += 4;   // stride/4 odd: bank decorrelation
    const int nq4 = stride >> 2;

    // per-thread staging split (adaptive: keep all 256 threads loading)
    int qq, r00, rstep;
    if (nq4 <= 8)       { qq = tid & 7;  r00 = tid >> 3; rstep = 32; }
    else if (nq4 <= 16) { qq = tid & 15; r00 = tid >> 4; rstep = 16; }
    else                { qq = tid & 31; r00 = tid >> 5; rstep = 8;  }
    // bh <= 8*rstep: the unrolled 8-deep register prefetch covers all rows
    // (violated only for pathological clamped bboxes; falls back, bit-identical)
    const bool staged = (stride * bh <= LDSC) && (nq4 <= 32) && (bh <= (rstep << 3));

    float nrm[4] = {0.0f, 0.0f, 0.0f, 0.0f};

    if (staged) {
        int l00[4], l01[4], u0x[4];
#pragma unroll
        for (int j = 0; j < 4; ++j) {
            const int r0 = (yi0a[j] - ylo) * stride - xlo;
            const int r1 = (yi1a[j] - ylo) * stride - xlo;
            l00[j] = r0 + xi0a[j];
            l01[j] = r1 + xi0a[j];
            u0x[j] = xi1a[j] - xi0a[j];    // 0 or 1; 0 only when x-clamped
        }
        const int col = xlo + (qq << 2);
        const bool doload = (col <= xhi);
        float* bufA = tileLds;
        float* bufB = tileLds + LDSC;

        vfloat4 pf[8];

        // T14 async channel pipeline:
        //   issue loads(c+1) -> regs  BEFORE compute(c); ds_write after barrier.
        // ch(c+1)'s global latency hides under ch(c)'s LDS+FMA compute.
#define ISSUE_LOADS(C)                                                        \
        _Pragma("unroll")                                                     \
        for (int u = 0; u < 8; ++u) {                                         \
            const int r = r00 + u * rstep;                                    \
            if (doload && r < bh)                                             \
                pf[u] = *(const vfloat4*)(orig_b + (C) * PLANE                \
                                          + (ylo + r) * IMG_W + col);         \
        }
#define WRITE_LDS(BUF)                                                        \
        _Pragma("unroll")                                                     \
        for (int u = 0; u < 8; ++u) {                                         \
            const int r = r00 + u * rstep;                                    \
            if (doload && r < bh)                                             \
                *(vfloat4*)(&(BUF)[r * stride + (qq << 2)]) = pf[u];          \
        }
#define COMPUTE_CH(BUF, RV)                                                   \
        {                                                                     \
            const vfloat4 rv = (RV);                                          \
            const float rj[4] = {rv.x, rv.y, rv.z, rv.w};                     \
            _Pragma("unroll")                                                 \
            for (int j = 0; j < 4; ++j) {                                     \
                const float a0 = (BUF)[l00[j]];                               \
                const float a1 = (BUF)[l00[j] + 1];                           \
                const float b0 = (BUF)[l01[j]];                               \
                const float b1 = (BUF)[l01[j] + 1];                           \
                const float s10 = u0x[j] ? a1 : a0;                           \
                const float s11 = u0x[j] ? b1 : b0;                           \
                const float warped = a0 * w00[j] + s10 * w10[j]               \
                                   + b0 * w01[j] + s11 * w11[j];              \
                nrm[j] += fabsf(rj[j] - warped);                              \
            }                                                                 \
        }

        ISSUE_LOADS(0)                 // ch0: exposed latency (head only)
        WRITE_LDS(bufA)
        __syncthreads();

        ISSUE_LOADS(1)                 // ch1 loads fly during ch0 compute
        COMPUTE_CH(bufA, rv0)
        WRITE_LDS(bufB)
        __syncthreads();               // bufA reads done + bufB ready

        ISSUE_LOADS(2)                 // ch2 loads fly during ch1 compute
        COMPUTE_CH(bufB, rv1)
        WRITE_LDS(bufA)                // bufA free (reads drained at last barrier)
        __syncthreads();

        COMPUTE_CH(bufA, rv2)

#undef ISSUE_LOADS
#undef WRITE_LDS
#undef COMPUTE_CH
    } else {
        // direct-gather fallback (minification blocks: little reuse anyway)
        int a0i[4], a1i[4], sl0[4], sl1[4];
#pragma unroll
        for (int j = 0; j < 4; ++j) {
            const int xc = min(xi0a[j], 510);
            a0i[j] = yi0a[j] * IMG_W + xc;
            a1i[j] = yi1a[j] * IMG_W + xc;
            sl0[j] = xi0a[j] - xc;
            sl1[j] = xi1a[j] - xc;
        }
#pragma unroll
        for (int c = 0; c < NC; ++c) {
            const float* plane = orig_b + c * PLANE;
            const vfloat4 rv = (c == 0) ? rv0 : (c == 1) ? rv1 : rv2;
            const float rj[4] = {rv.x, rv.y, rv.z, rv.w};
#pragma unroll
            for (int j = 0; j < 4; ++j) {
                const float2 t0 = *(const float2*)(plane + a0i[j]);
                const float2 t1 = *(const float2*)(plane + a1i[j]);
                const float s00 = sl0[j] ? t0.y : t0.x;
                const float s10 = sl1[j] ? t0.y : t0.x;
                const float s01 = sl0[j] ? t1.y : t1.x;
                const float s11 = sl1[j] ? t1.y : t1.x;
                const float warped = s00 * w00[j] + s10 * w10[j]
                                   + s01 * w01[j] + s11 * w11[j];
                nrm[j] += fabsf(rj[j] - warped);
            }
        }
    }

    float num_acc = 0.0f;
#pragma unroll
    for (int j = 0; j < 4; ++j) num_acc += mk[j] * nrm[j];

    // --- wave (64) reduction ---
#pragma unroll
    for (int off = 32; off > 0; off >>= 1) {
        num_acc += __shfl_down(num_acc, off);
        den_acc += __shfl_down(den_acc, off);
    }

    const int wave = threadIdx.x >> 6;
    const int lane = threadIdx.x & 63;
    if (lane == 0) { snum[wave] = num_acc; sden[wave] = den_acc; }
    __syncthreads();
    if (threadIdx.x == 0) {
        ws[gcan]           = snum[0] + snum[1] + snum[2] + snum[3];
        ws[NBLOCKS + gcan] = sden[0] + sden[1] + sden[2] + sden[3];
    }
}

__global__ __launch_bounds__(256) void recon_final(
    const float* __restrict__ ws,
    float* __restrict__ out)
{
    __shared__ float sloss[NB];
    const int t = threadIdx.x;
    const int b = t >> 3;              // 0..31 (8 threads per batch)
    const int j = t & 7;               // 0..7

    // canonical ws layout; same per-lane tile order as before (j*32+k ascending)
    float n = 0.0f, d = 0.0f;
    for (int k = 0; k < 32; ++k) {
        const int tile = j * 32 + k;
        const int g    = b * TILES_PER_B + tile;
        n += ws[g];
        d += ws[NBLOCKS + g];
    }
#pragma unroll
    for (int off = 4; off > 0; off >>= 1) {
        n += __shfl_down(n, off);
        d += __shfl_down(d, off);
    }
    if (j == 0) sloss[b] = 10.0f * (n + 1e-16f) / (d + 1e-16f);
    __syncthreads();
    if (t == 0) {
        float L = 0.0f;
#pragma unroll
        for (int i = 0; i < NB; ++i) L += sloss[i];
        out[0] = L * (1.0f / (float)NB);
    }
}

extern "C" void kernel_launch(void* const* d_in, const int* in_sizes, int n_in,
                              void* d_out, int out_size, void* d_ws, size_t ws_size,
                              hipStream_t stream) {
    const float* theta    = (const float*)d_in[0];
    const float* img_R    = (const float*)d_in[1];
    const float* img_orig = (const float*)d_in[2];
    float* out = (float*)d_out;
    float* ws  = (float*)d_ws;

    recon_main<<<NBLOCKS, 256, 0, stream>>>(theta, img_R, img_orig, ws);
    recon_final<<<1, 256, 0, stream>>>(ws, out);
}

// Round 7
// 216.643 us; speedup vs baseline: 1.2099x; 1.0286x over previous
//
#include <hip/hip_runtime.h>
#include <math.h>

#define IMG_W 512
#define IMG_H 512
#define NB 32
#define NC 3
#define PLANE (IMG_H * IMG_W)      // 262144 px per channel

#define TILE_W 32
#define TILE_H 32
#define TILES_X (IMG_W / TILE_W)   // 16
#define TILES_Y (IMG_H / TILE_H)   // 16
#define TILES_PER_B (TILES_X * TILES_Y)  // 256
#define NBLOCKS (NB * TILES_PER_B)       // 8192

#define LDSC 4096                  // per-channel staging floats (16 KB)
#define LDSF (3 * LDSC)            // 48 KB total -> 3 blocks/CU
#define CONS_OFF (2 * NBLOCKS)     // ws float-offset of per-batch constants

typedef float vfloat4 __attribute__((ext_vector_type(4)));

// ws layout: ws[b*256+tile]=num, ws[NBLOCKS+...]=den, ws[CONS_OFF+4b..]=consts.

__global__ __launch_bounds__(64) void recon_prep(
    const float* __restrict__ theta, float* __restrict__ ws)
{
    const int b = threadIdx.x;
    if (b < NB) {
        // EXACT same fp op sequence as the old in-block setup -> same bits
        const float ang   = theta[b * 3 + 0];
        const float s     = theta[b * 3 + 1];
        const float shift = 100.0f * theta[b * 3 + 2];
        float sn, cs;
        sincosf(ang, &sn, &cs);
        const float alpha = s * cs;
        const float beta  = s * sn;
        const float tx_a = (1.0f - alpha) * 256.0f - beta * 256.0f + shift;
        const float ty_a = beta * 256.0f + (1.0f - alpha) * 256.0f;
        const float Cc = alpha + beta + 2.0f * tx_a / 511.0f - 1.0f;
        const float Fc = -beta + alpha + 2.0f * ty_a / 511.0f - 1.0f;
        const float X0 = 255.5f * (Cc + 1.0f - alpha - beta);
        const float Y0 = 255.5f * (Fc + 1.0f + beta - alpha);
        ws[CONS_OFF + 4 * b + 0] = alpha;
        ws[CONS_OFF + 4 * b + 1] = beta;
        ws[CONS_OFF + 4 * b + 2] = X0;
        ws[CONS_OFF + 4 * b + 3] = Y0;
    }
}

__global__ __launch_bounds__(256, 3) void recon_main(
    const float* __restrict__ img_R,
    const float* __restrict__ img_orig,
    float* __restrict__ ws)
{
    __shared__ __align__(16) float tileLds[LDSF + 8];
    __shared__ float snum[4];
    __shared__ float sden[4];

    // --- load-balanced decode: each of the 8 dispatch streams (lin%8, ~XCD)
    // processes 1/8 of EVERY batch in 32-tile chunks. Bijective lin <-> (b,tile).
    const int lin  = blockIdx.x;       // 0..8191
    const int k    = lin & 7;          // stream id
    const int i    = lin >> 3;         // 0..1023
    const int step = i >> 5;           // 0..31
    const int t    = i & 31;           // 0..31 tile within chunk
    const int b    = (4 * k + step) & 31;
    const int chk  = ((b >> 2) - k) & 7;
    const int tile = chk * 32 + t;     // 0..255
    const int tx = (tile & (TILES_X - 1)) * TILE_W;
    const int ty = (tile >> 4) * TILE_H;
    const int gcan = b * TILES_PER_B + tile;   // canonical ws slot

    const int tid  = threadIdx.x;
    const int trow = tid >> 3;         // 0..31 (8 threads per tile row)
    const int tcol = (tid & 7) * 4;    // 0..28

    const int h  = ty + trow;
    const int w0 = tx + tcol;
    const int p0 = h * IMG_W + w0;

    const float* orig_b = img_orig + (size_t)b * NC * PLANE;
    const float* R_b    = img_R    + (size_t)b * NC * PLANE;

    // --- per-batch constants: one uniform 16B load (prep kernel did sincos)
    const vfloat4 cb = *(const vfloat4*)(ws + CONS_OFF + 4 * b);
    const float alpha = cb.x, beta = cb.y, X0 = cb.z, Y0 = cb.w;

    // --- block-uniform source bbox (extrema at tile corners) ---
    const float fx_lo = (float)tx, fx_hi = (float)(tx + TILE_W - 1);
    const float fy_lo = (float)ty, fy_hi = (float)(ty + TILE_H - 1);
    const float cxA = X0 + alpha * fx_lo + beta * fy_lo;
    const float cxB = X0 + alpha * fx_hi + beta * fy_lo;
    const float cxC = X0 + alpha * fx_lo + beta * fy_hi;
    const float cxD = X0 + alpha * fx_hi + beta * fy_hi;
    const float cyA = Y0 - beta * fx_lo + alpha * fy_lo;
    const float cyB = Y0 - beta * fx_hi + alpha * fy_lo;
    const float cyC = Y0 - beta * fx_lo + alpha * fy_hi;
    const float cyD = Y0 - beta * fx_hi + alpha * fy_hi;
    const float min_x = fminf(fminf(cxA, cxB), fminf(cxC, cxD));
    const float max_x = fmaxf(fmaxf(cxA, cxB), fmaxf(cxC, cxD));
    const float min_y = fminf(fminf(cyA, cyB), fminf(cyC, cyD));
    const float max_y = fmaxf(fmaxf(cyA, cyB), fmaxf(cyC, cyD));

    // --- exact OOB skip: bbox misses image -> ALL weights are exactly 0
    // -> num = den = 0.0 bit-exactly. Skip all loads/staging/compute.
    const bool oob = (max_x < 0.0f) || (min_x > 511.0f) ||
                     (max_y < 0.0f) || (min_y > 511.0f);

    float num_acc = 0.0f, den_acc = 0.0f;

    if (!oob) {
        int xlo = (int)floorf(min_x);
        int xhi = (int)floorf(max_x) + 1;
        xlo = min(max(xlo, 0), 511);
        xhi = min(max(xhi, 0), 511);
        xlo &= ~3;                      // 16B-align staging rows
        int ylo = (int)floorf(min_y);
        int yhi = (int)floorf(max_y) + 1;
        ylo = min(max(ylo, 0), 511);
        yhi = min(max(yhi, 0), 511);

        const int bw = xhi - xlo + 1;
        const int bh = yhi - ylo + 1;
        int stride = (bw + 3) & ~3;
        if (((stride >> 2) & 1) == 0) stride += 4;   // stride/4 odd: bank decorrelation
        const int nq4 = stride >> 2;
        const bool staged = (stride * bh <= LDSC) && (nq4 <= 32);

        // adaptive staging split: keep all 256 threads loading
        int qq, r00, rstep;
        if (nq4 <= 8)       { qq = tid & 7;  r00 = tid >> 3; rstep = 32; }
        else if (nq4 <= 16) { qq = tid & 15; r00 = tid >> 4; rstep = 16; }
        else                { qq = tid & 31; r00 = tid >> 5; rstep = 8;  }
        const int col = xlo + (qq << 2);
        const bool doload = staged && (col <= xhi);

        const float xb = X0 + alpha * (float)w0 + beta * (float)h;
        const float yb = Y0 - beta * (float)w0 + alpha * (float)h;

        int   xi0a[4], xi1a[4], yi0a[4], yi1a[4];
        float w00[4], w10[4], w01[4], w11[4], mk[4];
        float nrm[4] = {0.0f, 0.0f, 0.0f, 0.0f};

        if (staged) {
            // ---- T14 issue-early: ALL staging loads (4-deep x 3ch) + R loads
            // fly while the ~150-VALU weight block computes in their shadow.
            const int r1 = r00 + rstep, r2 = r00 + 2 * rstep, r3 = r00 + 3 * rstep;
            const bool v0 = doload && (r00 < bh);
            const bool v1 = doload && (r1  < bh);
            const bool v2 = doload && (r2  < bh);
            const bool v3 = doload && (r3  < bh);
            vfloat4 pf0[3], pf1[3], pf2[3], pf3[3];
            const float* src0 = orig_b + (ylo + r00) * IMG_W + col;
            const float* src1 = orig_b + (ylo + r1)  * IMG_W + col;
            const float* src2 = orig_b + (ylo + r2)  * IMG_W + col;
            const float* src3 = orig_b + (ylo + r3)  * IMG_W + col;
            if (v0) {
#pragma unroll
                for (int c = 0; c < NC; ++c) pf0[c] = *(const vfloat4*)(src0 + c * PLANE);
            }
            if (v1) {
#pragma unroll
                for (int c = 0; c < NC; ++c) pf1[c] = *(const vfloat4*)(src1 + c * PLANE);
            }
            if (v2) {
#pragma unroll
                for (int c = 0; c < NC; ++c) pf2[c] = *(const vfloat4*)(src2 + c * PLANE);
            }
            if (v3) {
#pragma unroll
                for (int c = 0; c < NC; ++c) pf3[c] = *(const vfloat4*)(src3 + c * PLANE);
            }
            const vfloat4 rv0 = *(const vfloat4*)(R_b + 0 * PLANE + p0);
            const vfloat4 rv1 = *(const vfloat4*)(R_b + 1 * PLANE + p0);
            const vfloat4 rv2 = *(const vfloat4*)(R_b + 2 * PLANE + p0);

            // ---- weights (in the shadow of the in-flight loads) ----
#pragma unroll
            for (int j = 0; j < 4; ++j) {
                const float x = xb + alpha * (float)j;
                const float y = yb - beta  * (float)j;
                const float x0f = floorf(x), y0f = floorf(y);
                const float fx1 = x - x0f,  fy1 = y - y0f;
                const float fx0 = 1.0f - fx1, fy0 = 1.0f - fy1;
                const float vx0 = (x0f >=  0.0f && x0f <= 511.0f) ? 1.0f : 0.0f;
                const float vx1 = (x0f >= -1.0f && x0f <= 510.0f) ? 1.0f : 0.0f;
                const float vy0 = (y0f >=  0.0f && y0f <= 511.0f) ? 1.0f : 0.0f;
                const float vy1 = (y0f >= -1.0f && y0f <= 510.0f) ? 1.0f : 0.0f;
                xi0a[j] = (int)fminf(fmaxf(x0f,        0.0f), 511.0f);
                xi1a[j] = (int)fminf(fmaxf(x0f + 1.0f, 0.0f), 511.0f);
                yi0a[j] = (int)fminf(fmaxf(y0f,        0.0f), 511.0f);
                yi1a[j] = (int)fminf(fmaxf(y0f + 1.0f, 0.0f), 511.0f);
                w00[j] = fx0 * fy0 * vx0 * vy0;
                w10[j] = fx1 * fy0 * vx1 * vy0;
                w01[j] = fx0 * fy1 * vx0 * vy1;
                w11[j] = fx1 * fy1 * vx1 * vy1;
                mk[j]  = w00[j] + w10[j] + w01[j] + w11[j];
                den_acc += mk[j];
            }
            int l00[4], l01[4], u0x[4];
#pragma unroll
            for (int j = 0; j < 4; ++j) {
                const int r0i = (yi0a[j] - ylo) * stride - xlo;
                const int r1i = (yi1a[j] - ylo) * stride - xlo;
                l00[j] = r0i + xi0a[j];
                l01[j] = r1i + xi0a[j];
                u0x[j] = xi1a[j] - xi0a[j];    // 0 or 1; 0 only when x-clamped
            }

            // ---- write-late: vmcnt waits land here, after the VALU shadow ----
            if (v0) {
                float* dst = &tileLds[r00 * stride + (qq << 2)];
#pragma unroll
                for (int c = 0; c < NC; ++c) *(vfloat4*)(dst + c * LDSC) = pf0[c];
            }
            if (v1) {
                float* dst = &tileLds[r1 * stride + (qq << 2)];
#pragma unroll
                for (int c = 0; c < NC; ++c) *(vfloat4*)(dst + c * LDSC) = pf1[c];
            }
            if (v2) {
                float* dst = &tileLds[r2 * stride + (qq << 2)];
#pragma unroll
                for (int c = 0; c < NC; ++c) *(vfloat4*)(dst + c * LDSC) = pf2[c];
            }
            if (v3) {
                float* dst = &tileLds[r3 * stride + (qq << 2)];
#pragma unroll
                for (int c = 0; c < NC; ++c) *(vfloat4*)(dst + c * LDSC) = pf3[c];
            }
            // residual rows (rare narrow-tall bboxes: bh > 4*rstep)
            if (doload) {
                for (int r = r00 + 4 * rstep; r < bh; r += rstep) {
                    const float* src = orig_b + (ylo + r) * IMG_W + col;
                    float* dst = &tileLds[r * stride + (qq << 2)];
#pragma unroll
                    for (int c = 0; c < NC; ++c)
                        *(vfloat4*)(dst + c * LDSC) = *(const vfloat4*)(src + c * PLANE);
                }
            }
            __syncthreads();

#pragma unroll
            for (int c = 0; c < NC; ++c) {
                const vfloat4 rv = (c == 0) ? rv0 : (c == 1) ? rv1 : rv2;
                const float rj[4] = {rv.x, rv.y, rv.z, rv.w};
                const float* buf = &tileLds[c * LDSC];
#pragma unroll
                for (int j = 0; j < 4; ++j) {
                    const float a0 = buf[l00[j]];
                    const float a1 = buf[l00[j] + 1];
                    const float b0 = buf[l01[j]];
                    const float b1 = buf[l01[j] + 1];
                    const float s10 = u0x[j] ? a1 : a0;
                    const float s11 = u0x[j] ? b1 : b0;
                    const float warped = a0 * w00[j] + s10 * w10[j]
                                       + b0 * w01[j] + s11 * w11[j];
                    nrm[j] += fabsf(rj[j] - warped);
                }
            }
        } else {
            // direct-gather fallback (minification blocks: little reuse anyway)
            const vfloat4 rv0 = *(const vfloat4*)(R_b + 0 * PLANE + p0);
            const vfloat4 rv1 = *(const vfloat4*)(R_b + 1 * PLANE + p0);
            const vfloat4 rv2 = *(const vfloat4*)(R_b + 2 * PLANE + p0);
#pragma unroll
            for (int j = 0; j < 4; ++j) {
                const float x = xb + alpha * (float)j;
                const float y = yb - beta  * (float)j;
                const float x0f = floorf(x), y0f = floorf(y);
                const float fx1 = x - x0f,  fy1 = y - y0f;
                const float fx0 = 1.0f - fx1, fy0 = 1.0f - fy1;
                const float vx0 = (x0f >=  0.0f && x0f <= 511.0f) ? 1.0f : 0.0f;
                const float vx1 = (x0f >= -1.0f && x0f <= 510.0f) ? 1.0f : 0.0f;
                const float vy0 = (y0f >=  0.0f && y0f <= 511.0f) ? 1.0f : 0.0f;
                const float vy1 = (y0f >= -1.0f && y0f <= 510.0f) ? 1.0f : 0.0f;
                xi0a[j] = (int)fminf(fmaxf(x0f,        0.0f), 511.0f);
                xi1a[j] = (int)fminf(fmaxf(x0f + 1.0f, 0.0f), 511.0f);
                yi0a[j] = (int)fminf(fmaxf(y0f,        0.0f), 511.0f);
                yi1a[j] = (int)fminf(fmaxf(y0f + 1.0f, 0.0f), 511.0f);
                w00[j] = fx0 * fy0 * vx0 * vy0;
                w10[j] = fx1 * fy0 * vx1 * vy0;
                w01[j] = fx0 * fy1 * vx0 * vy1;
                w11[j] = fx1 * fy1 * vx1 * vy1;
                mk[j]  = w00[j] + w10[j] + w01[j] + w11[j];
                den_acc += mk[j];
            }
            int a0i[4], a1i[4], sl0[4], sl1[4];
#pragma unroll
            for (int j = 0; j < 4; ++j) {
                const int xc = min(xi0a[j], 510);
                a0i[j] = yi0a[j] * IMG_W + xc;
                a1i[j] = yi1a[j] * IMG_W + xc;
                sl0[j] = xi0a[j] - xc;
                sl1[j] = xi1a[j] - xc;
            }
#pragma unroll
            for (int c = 0; c < NC; ++c) {
                const float* plane = orig_b + c * PLANE;
                const vfloat4 rv = (c == 0) ? rv0 : (c == 1) ? rv1 : rv2;
                const float rj[4] = {rv.x, rv.y, rv.z, rv.w};
#pragma unroll
                for (int j = 0; j < 4; ++j) {
                    const float2 t0 = *(const float2*)(plane + a0i[j]);
                    const float2 t1 = *(const float2*)(plane + a1i[j]);
                    const float s00 = sl0[j] ? t0.y : t0.x;
                    const float s10 = sl1[j] ? t0.y : t0.x;
                    const float s01 = sl0[j] ? t1.y : t1.x;
                    const float s11 = sl1[j] ? t1.y : t1.x;
                    const float warped = s00 * w00[j] + s10 * w10[j]
                                       + s01 * w01[j] + s11 * w11[j];
                    nrm[j] += fabsf(rj[j] - warped);
                }
            }
        }

#pragma unroll
        for (int j = 0; j < 4; ++j) num_acc += mk[j] * nrm[j];
    }

    // --- wave (64) reduction ---
#pragma unroll
    for (int off = 32; off > 0; off >>= 1) {
        num_acc += __shfl_down(num_acc, off);
        den_acc += __shfl_down(den_acc, off);
    }

    const int wave = threadIdx.x >> 6;
    const int lane = threadIdx.x & 63;
    if (lane == 0) { snum[wave] = num_acc; sden[wave] = den_acc; }
    __syncthreads();
    if (threadIdx.x == 0) {
        ws[gcan]           = snum[0] + snum[1] + snum[2] + snum[3];
        ws[NBLOCKS + gcan] = sden[0] + sden[1] + sden[2] + sden[3];
    }
}

__global__ __launch_bounds__(256) void recon_final(
    const float* __restrict__ ws,
    float* __restrict__ out)
{
    __shared__ float sloss[NB];
    const int t = threadIdx.x;
    const int b = t >> 3;              // 0..31 (8 threads per batch)
    const int j = t & 7;               // 0..7

    float n = 0.0f, d = 0.0f;
    for (int k = 0; k < 32; ++k) {
        const int tile = j * 32 + k;
        const int g    = b * TILES_PER_B + tile;
        n += ws[g];
        d += ws[NBLOCKS + g];
    }
#pragma unroll
    for (int off = 4; off > 0; off >>= 1) {
        n += __shfl_down(n, off);
        d += __shfl_down(d, off);
    }
    if (j == 0) sloss[b] = 10.0f * (n + 1e-16f) / (d + 1e-16f);
    __syncthreads();
    if (t == 0) {
        float L = 0.0f;
#pragma unroll
        for (int i = 0; i < NB; ++i) L += sloss[i];
        out[0] = L * (1.0f / (float)NB);
    }
}

extern "C" void kernel_launch(void* const* d_in, const int* in_sizes, int n_in,
                              void* d_out, int out_size, void* d_ws, size_t ws_size,
                              hipStream_t stream) {
    const float* theta    = (const float*)d_in[0];
    const float* img_R    = (const float*)d_in[1];
    const float* img_orig = (const float*)d_in[2];
    float* out = (float*)d_out;
    float* ws  = (float*)d_ws;

    recon_prep<<<1, 64, 0, stream>>>(theta, ws);
    recon_main<<<NBLOCKS, 256, 0, stream>>>(img_R, img_orig, ws);
    recon_final<<<1, 256, 0, stream>>>(ws, out);
}

// Round 8
// 213.372 us; speedup vs baseline: 1.2284x; 1.0153x over previous
//
#include <hip/hip_runtime.h>
#include <math.h>

#define IMG_W 512
#define IMG_H 512
#define NB 32
#define NC 3
#define PLANE (IMG_H * IMG_W)      // 262144 px per channel

#define TILE_W 32
#define TILE_H 32
#define TILES_X (IMG_W / TILE_W)   // 16
#define TILES_Y (IMG_H / TILE_H)   // 16
#define TILES_PER_B (TILES_X * TILES_Y)  // 256
#define NBLOCKS (NB * TILES_PER_B)       // 8192

// LDSC=3408: 3*3408+16 floats = 40928 B -> 40960 B after 512B-granule rounding
// -> EXACTLY 4 blocks/CU on the 160 KiB pool (was 4096 -> 49664 B -> 3/CU).
#define LDSC 3408
#define CONS_OFF (2 * NBLOCKS)     // ws float-offset of per-batch constants

typedef float vfloat4 __attribute__((ext_vector_type(4)));

// ws layout: ws[b*256+tile]=num, ws[NBLOCKS+...]=den, ws[CONS_OFF+4b..]=consts.

__global__ __launch_bounds__(64) void recon_prep(
    const float* __restrict__ theta, float* __restrict__ ws)
{
    const int b = threadIdx.x;
    if (b < NB) {
        // EXACT same fp op sequence as the old in-block setup -> same bits
        const float ang   = theta[b * 3 + 0];
        const float s     = theta[b * 3 + 1];
        const float shift = 100.0f * theta[b * 3 + 2];
        float sn, cs;
        sincosf(ang, &sn, &cs);
        const float alpha = s * cs;
        const float beta  = s * sn;
        const float tx_a = (1.0f - alpha) * 256.0f - beta * 256.0f + shift;
        const float ty_a = beta * 256.0f + (1.0f - alpha) * 256.0f;
        const float Cc = alpha + beta + 2.0f * tx_a / 511.0f - 1.0f;
        const float Fc = -beta + alpha + 2.0f * ty_a / 511.0f - 1.0f;
        const float X0 = 255.5f * (Cc + 1.0f - alpha - beta);
        const float Y0 = 255.5f * (Fc + 1.0f + beta - alpha);
        ws[CONS_OFF + 4 * b + 0] = alpha;
        ws[CONS_OFF + 4 * b + 1] = beta;
        ws[CONS_OFF + 4 * b + 2] = X0;
        ws[CONS_OFF + 4 * b + 3] = Y0;
    }
}

__global__ __launch_bounds__(256, 4) void recon_main(
    const float* __restrict__ img_R,
    const float* __restrict__ img_orig,
    float* __restrict__ ws)
{
    __shared__ __align__(16) float tileLds[3 * LDSC];
    __shared__ float snum[4];
    __shared__ float sden[4];

    // --- load-balanced decode: each of the 8 dispatch streams (lin%8, ~XCD)
    // processes 1/8 of EVERY batch in 32-tile chunks. Bijective lin <-> (b,tile).
    const int lin  = blockIdx.x;       // 0..8191
    const int k    = lin & 7;          // stream id
    const int i    = lin >> 3;         // 0..1023
    const int step = i >> 5;           // 0..31
    const int t    = i & 31;           // 0..31 tile within chunk
    const int b    = (4 * k + step) & 31;
    const int chk  = ((b >> 2) - k) & 7;
    const int tile = chk * 32 + t;     // 0..255
    const int tx = (tile & (TILES_X - 1)) * TILE_W;
    const int ty = (tile >> 4) * TILE_H;
    const int gcan = b * TILES_PER_B + tile;   // canonical ws slot

    const int tid  = threadIdx.x;
    const int trow = tid >> 3;         // 0..31 (8 threads per tile row)
    const int tcol = (tid & 7) * 4;    // 0..28

    const int h  = ty + trow;
    const int w0 = tx + tcol;
    const int p0 = h * IMG_W + w0;

    const float* orig_b = img_orig + (size_t)b * NC * PLANE;
    const float* R_b    = img_R    + (size_t)b * NC * PLANE;

    // --- per-batch constants: one uniform 16B load (prep kernel did sincos)
    const vfloat4 cb = *(const vfloat4*)(ws + CONS_OFF + 4 * b);
    const float alpha = cb.x, beta = cb.y, X0 = cb.z, Y0 = cb.w;

    // --- block-uniform source bbox (extrema at tile corners) ---
    const float fx_lo = (float)tx, fx_hi = (float)(tx + TILE_W - 1);
    const float fy_lo = (float)ty, fy_hi = (float)(ty + TILE_H - 1);
    const float cxA = X0 + alpha * fx_lo + beta * fy_lo;
    const float cxB = X0 + alpha * fx_hi + beta * fy_lo;
    const float cxC = X0 + alpha * fx_lo + beta * fy_hi;
    const float cxD = X0 + alpha * fx_hi + beta * fy_hi;
    const float cyA = Y0 - beta * fx_lo + alpha * fy_lo;
    const float cyB = Y0 - beta * fx_hi + alpha * fy_lo;
    const float cyC = Y0 - beta * fx_lo + alpha * fy_hi;
    const float cyD = Y0 - beta * fx_hi + alpha * fy_hi;
    const float min_x = fminf(fminf(cxA, cxB), fminf(cxC, cxD));
    const float max_x = fmaxf(fmaxf(cxA, cxB), fmaxf(cxC, cxD));
    const float min_y = fminf(fminf(cyA, cyB), fminf(cyC, cyD));
    const float max_y = fmaxf(fmaxf(cyA, cyB), fmaxf(cyC, cyD));

    // --- exact OOB skip: bbox misses image -> ALL weights are exactly 0
    // -> num = den = 0.0 bit-exactly. Skip all loads/staging/compute.
    const bool oob = (max_x < 0.0f) || (min_x > 511.0f) ||
                     (max_y < 0.0f) || (min_y > 511.0f);

    float num_acc = 0.0f, den_acc = 0.0f;

    if (!oob) {
        int xlo = (int)floorf(min_x);
        int xhi = (int)floorf(max_x) + 1;
        xlo = min(max(xlo, 0), 511);
        xhi = min(max(xhi, 0), 511);
        xlo &= ~3;                      // 16B-align staging rows
        int ylo = (int)floorf(min_y);
        int yhi = (int)floorf(max_y) + 1;
        ylo = min(max(ylo, 0), 511);
        yhi = min(max(yhi, 0), 511);

        const int bw = xhi - xlo + 1;
        const int bh = yhi - ylo + 1;
        int stride = (bw + 3) & ~3;
        if (((stride >> 2) & 1) == 0) stride += 4;   // stride/4 odd: bank decorrelation
        const int nq4 = stride >> 2;
        const bool staged = (stride * bh <= LDSC) && (nq4 <= 32);

        // adaptive staging split: keep all 256 threads loading
        int qq, r00, rstep;
        if (nq4 <= 8)       { qq = tid & 7;  r00 = tid >> 3; rstep = 32; }
        else if (nq4 <= 16) { qq = tid & 15; r00 = tid >> 4; rstep = 16; }
        else                { qq = tid & 31; r00 = tid >> 5; rstep = 8;  }
        const int col = xlo + (qq << 2);
        const bool doload = staged && (col <= xhi);

        const float xb = X0 + alpha * (float)w0 + beta * (float)h;
        const float yb = Y0 - beta * (float)w0 + alpha * (float)h;

        int   xi0a[4], xi1a[4], yi0a[4], yi1a[4];
        float w00[4], w10[4], w01[4], w11[4], mk[4];
        float nrm[4] = {0.0f, 0.0f, 0.0f, 0.0f};

        if (staged) {
            // ---- T14 issue-early: ALL staging loads (4-deep x 3ch) + R loads
            // fly while the ~150-VALU weight block computes in their shadow.
            const int r1 = r00 + rstep, r2 = r00 + 2 * rstep, r3 = r00 + 3 * rstep;
            const bool v0 = doload && (r00 < bh);
            const bool v1 = doload && (r1  < bh);
            const bool v2 = doload && (r2  < bh);
            const bool v3 = doload && (r3  < bh);
            vfloat4 pf0[3], pf1[3], pf2[3], pf3[3];
            const float* src0 = orig_b + (ylo + r00) * IMG_W + col;
            const float* src1 = orig_b + (ylo + r1)  * IMG_W + col;
            const float* src2 = orig_b + (ylo + r2)  * IMG_W + col;
            const float* src3 = orig_b + (ylo + r3)  * IMG_W + col;
            if (v0) {
#pragma unroll
                for (int c = 0; c < NC; ++c) pf0[c] = *(const vfloat4*)(src0 + c * PLANE);
            }
            if (v1) {
#pragma unroll
                for (int c = 0; c < NC; ++c) pf1[c] = *(const vfloat4*)(src1 + c * PLANE);
            }
            if (v2) {
#pragma unroll
                for (int c = 0; c < NC; ++c) pf2[c] = *(const vfloat4*)(src2 + c * PLANE);
            }
            if (v3) {
#pragma unroll
                for (int c = 0; c < NC; ++c) pf3[c] = *(const vfloat4*)(src3 + c * PLANE);
            }
            const vfloat4 rv0 = *(const vfloat4*)(R_b + 0 * PLANE + p0);
            const vfloat4 rv1 = *(const vfloat4*)(R_b + 1 * PLANE + p0);
            const vfloat4 rv2 = *(const vfloat4*)(R_b + 2 * PLANE + p0);

            // ---- weights (in the shadow of the in-flight loads) ----
#pragma unroll
            for (int j = 0; j < 4; ++j) {
                const float x = xb + alpha * (float)j;
                const float y = yb - beta  * (float)j;
                const float x0f = floorf(x), y0f = floorf(y);
                const float fx1 = x - x0f,  fy1 = y - y0f;
                const float fx0 = 1.0f - fx1, fy0 = 1.0f - fy1;
                const float vx0 = (x0f >=  0.0f && x0f <= 511.0f) ? 1.0f : 0.0f;
                const float vx1 = (x0f >= -1.0f && x0f <= 510.0f) ? 1.0f : 0.0f;
                const float vy0 = (y0f >=  0.0f && y0f <= 511.0f) ? 1.0f : 0.0f;
                const float vy1 = (y0f >= -1.0f && y0f <= 510.0f) ? 1.0f : 0.0f;
                xi0a[j] = (int)fminf(fmaxf(x0f,        0.0f), 511.0f);
                xi1a[j] = (int)fminf(fmaxf(x0f + 1.0f, 0.0f), 511.0f);
                yi0a[j] = (int)fminf(fmaxf(y0f,        0.0f), 511.0f);
                yi1a[j] = (int)fminf(fmaxf(y0f + 1.0f, 0.0f), 511.0f);
                w00[j] = fx0 * fy0 * vx0 * vy0;
                w10[j] = fx1 * fy0 * vx1 * vy0;
                w01[j] = fx0 * fy1 * vx0 * vy1;
                w11[j] = fx1 * fy1 * vx1 * vy1;
                mk[j]  = w00[j] + w10[j] + w01[j] + w11[j];
                den_acc += mk[j];
            }
            int l00[4], l01[4], u0x[4];
#pragma unroll
            for (int j = 0; j < 4; ++j) {
                const int r0i = (yi0a[j] - ylo) * stride - xlo;
                const int r1i = (yi1a[j] - ylo) * stride - xlo;
                l00[j] = r0i + xi0a[j];
                l01[j] = r1i + xi0a[j];
                u0x[j] = xi1a[j] - xi0a[j];    // 0 or 1; 0 only when x-clamped
            }

            // ---- write-late: vmcnt waits land here, after the VALU shadow ----
            if (v0) {
                float* dst = &tileLds[r00 * stride + (qq << 2)];
#pragma unroll
                for (int c = 0; c < NC; ++c) *(vfloat4*)(dst + c * LDSC) = pf0[c];
            }
            if (v1) {
                float* dst = &tileLds[r1 * stride + (qq << 2)];
#pragma unroll
                for (int c = 0; c < NC; ++c) *(vfloat4*)(dst + c * LDSC) = pf1[c];
            }
            if (v2) {
                float* dst = &tileLds[r2 * stride + (qq << 2)];
#pragma unroll
                for (int c = 0; c < NC; ++c) *(vfloat4*)(dst + c * LDSC) = pf2[c];
            }
            if (v3) {
                float* dst = &tileLds[r3 * stride + (qq << 2)];
#pragma unroll
                for (int c = 0; c < NC; ++c) *(vfloat4*)(dst + c * LDSC) = pf3[c];
            }
            // residual rows (rare narrow-tall bboxes: bh > 4*rstep)
            if (doload) {
                for (int r = r00 + 4 * rstep; r < bh; r += rstep) {
                    const float* src = orig_b + (ylo + r) * IMG_W + col;
                    float* dst = &tileLds[r * stride + (qq << 2)];
#pragma unroll
                    for (int c = 0; c < NC; ++c)
                        *(vfloat4*)(dst + c * LDSC) = *(const vfloat4*)(src + c * PLANE);
                }
            }
            __syncthreads();

#pragma unroll
            for (int c = 0; c < NC; ++c) {
                const vfloat4 rv = (c == 0) ? rv0 : (c == 1) ? rv1 : rv2;
                const float rj[4] = {rv.x, rv.y, rv.z, rv.w};
                const float* buf = &tileLds[c * LDSC];
#pragma unroll
                for (int j = 0; j < 4; ++j) {
                    const float a0 = buf[l00[j]];
                    const float a1 = buf[l00[j] + 1];
                    const float b0 = buf[l01[j]];
                    const float b1 = buf[l01[j] + 1];
                    const float s10 = u0x[j] ? a1 : a0;
                    const float s11 = u0x[j] ? b1 : b0;
                    const float warped = a0 * w00[j] + s10 * w10[j]
                                       + b0 * w01[j] + s11 * w11[j];
                    nrm[j] += fabsf(rj[j] - warped);
                }
            }
        } else {
            // direct-gather fallback (minification blocks: little reuse anyway)
            const vfloat4 rv0 = *(const vfloat4*)(R_b + 0 * PLANE + p0);
            const vfloat4 rv1 = *(const vfloat4*)(R_b + 1 * PLANE + p0);
            const vfloat4 rv2 = *(const vfloat4*)(R_b + 2 * PLANE + p0);
#pragma unroll
            for (int j = 0; j < 4; ++j) {
                const float x = xb + alpha * (float)j;
                const float y = yb - beta  * (float)j;
                const float x0f = floorf(x), y0f = floorf(y);
                const float fx1 = x - x0f,  fy1 = y - y0f;
                const float fx0 = 1.0f - fx1, fy0 = 1.0f - fy1;
                const float vx0 = (x0f >=  0.0f && x0f <= 511.0f) ? 1.0f : 0.0f;
                const float vx1 = (x0f >= -1.0f && x0f <= 510.0f) ? 1.0f : 0.0f;
                const float vy0 = (y0f >=  0.0f && y0f <= 511.0f) ? 1.0f : 0.0f;
                const float vy1 = (y0f >= -1.0f && y0f <= 510.0f) ? 1.0f : 0.0f;
                xi0a[j] = (int)fminf(fmaxf(x0f,        0.0f), 511.0f);
                xi1a[j] = (int)fminf(fmaxf(x0f + 1.0f, 0.0f), 511.0f);
                yi0a[j] = (int)fminf(fmaxf(y0f,        0.0f), 511.0f);
                yi1a[j] = (int)fminf(fmaxf(y0f + 1.0f, 0.0f), 511.0f);
                w00[j] = fx0 * fy0 * vx0 * vy0;
                w10[j] = fx1 * fy0 * vx1 * vy0;
                w01[j] = fx0 * fy1 * vx0 * vy1;
                w11[j] = fx1 * fy1 * vx1 * vy1;
                mk[j]  = w00[j] + w10[j] + w01[j] + w11[j];
                den_acc += mk[j];
            }
            int a0i[4], a1i[4], sl0[4], sl1[4];
#pragma unroll
            for (int j = 0; j < 4; ++j) {
                const int xc = min(xi0a[j], 510);
                a0i[j] = yi0a[j] * IMG_W + xc;
                a1i[j] = yi1a[j] * IMG_W + xc;
                sl0[j] = xi0a[j] - xc;
                sl1[j] = xi1a[j] - xc;
            }
#pragma unroll
            for (int c = 0; c < NC; ++c) {
                const float* plane = orig_b + c * PLANE;
                const vfloat4 rv = (c == 0) ? rv0 : (c == 1) ? rv1 : rv2;
                const float rj[4] = {rv.x, rv.y, rv.z, rv.w};
#pragma unroll
                for (int j = 0; j < 4; ++j) {
                    const float2 t0 = *(const float2*)(plane + a0i[j]);
                    const float2 t1 = *(const float2*)(plane + a1i[j]);
                    const float s00 = sl0[j] ? t0.y : t0.x;
                    const float s10 = sl1[j] ? t0.y : t0.x;
                    const float s01 = sl0[j] ? t1.y : t1.x;
                    const float s11 = sl1[j] ? t1.y : t1.x;
                    const float warped = s00 * w00[j] + s10 * w10[j]
                                       + s01 * w01[j] + s11 * w11[j];
                    nrm[j] += fabsf(rj[j] - warped);
                }
            }
        }

#pragma unroll
        for (int j = 0; j < 4; ++j) num_acc += mk[j] * nrm[j];
    }

    // --- wave (64) reduction ---
#pragma unroll
    for (int off = 32; off > 0; off >>= 1) {
        num_acc += __shfl_down(num_acc, off);
        den_acc += __shfl_down(den_acc, off);
    }

    const int wave = threadIdx.x >> 6;
    const int lane = threadIdx.x & 63;
    if (lane == 0) { snum[wave] = num_acc; sden[wave] = den_acc; }
    __syncthreads();
    if (threadIdx.x == 0) {
        ws[gcan]           = snum[0] + snum[1] + snum[2] + snum[3];
        ws[NBLOCKS + gcan] = sden[0] + sden[1] + sden[2] + sden[3];
    }
}

__global__ __launch_bounds__(256) void recon_final(
    const float* __restrict__ ws,
    float* __restrict__ out)
{
    __shared__ float sloss[NB];
    const int t = threadIdx.x;
    const int b = t >> 3;              // 0..31 (8 threads per batch)
    const int j = t & 7;               // 0..7

    float n = 0.0f, d = 0.0f;
    for (int k = 0; k < 32; ++k) {
        const int tile = j * 32 + k;
        const int g    = b * TILES_PER_B + tile;
        n += ws[g];
        d += ws[NBLOCKS + g];
    }
#pragma unroll
    for (int off = 4; off > 0; off >>= 1) {
        n += __shfl_down(n, off);
        d += __shfl_down(d, off);
    }
    if (j == 0) sloss[b] = 10.0f * (n + 1e-16f) / (d + 1e-16f);
    __syncthreads();
    if (t == 0) {
        float L = 0.0f;
#pragma unroll
        for (int i = 0; i < NB; ++i) L += sloss[i];
        out[0] = L * (1.0f / (float)NB);
    }
}

extern "C" void kernel_launch(void* const* d_in, const int* in_sizes, int n_in,
                              void* d_out, int out_size, void* d_ws, size_t ws_size,
                              hipStream_t stream) {
    const float* theta    = (const float*)d_in[0];
    const float* img_R    = (const float*)d_in[1];
    const float* img_orig = (const float*)d_in[2];
    float* out = (float*)d_out;
    float* ws  = (float*)d_ws;

    recon_prep<<<1, 64, 0, stream>>>(theta, ws);
    recon_main<<<NBLOCKS, 256, 0, stream>>>(img_R, img_orig, ws);
    recon_final<<<1, 256, 0, stream>>>(ws, out);
}